// Round 1
// baseline (401.141 us; speedup 1.0000x reference)
//
#include <hip/hip_runtime.h>
#include <hip/hip_bf16.h>

#define T_DIM   64
#define IN_DIM  4096
#define OUT_DIM 12288
#define NGROUP  32      // IN/GS
#define R_DIM   16
#define LR      64      // L*R

#define BN 48           // out-cols per block  -> grid = 12288/48 = 256 (one per CU)
#define BK 128          // k per chunk (== group size GS)
#define NCHUNK (IN_DIM / BK)   // 32
#define LDS_STRIDE (BK + 8)    // +8 bf16 pad: keeps 16B row alignment, breaks pow2 bank stride

typedef __bf16 bf16x4 __attribute__((ext_vector_type(4)));
typedef __bf16 bf16x8 __attribute__((ext_vector_type(8)));
typedef float  f32x4  __attribute__((ext_vector_type(4)));

// ---------------------------------------------------------------------------
// Kernel 1: t[t][c] = lora_scales[c/16] * dot(x[t,:], down[c,:])   (c = l*16+r)
// down is [L,R,IN] fp32 = row-major [64][4096]. Output t -> d_ws (64x64 fp32).
// ---------------------------------------------------------------------------
__global__ __launch_bounds__(256) void lora_down_kernel(
    const float* __restrict__ x, const float* __restrict__ down,
    const float* __restrict__ lora_scales, float* __restrict__ tbuf)
{
    __shared__ float d_lds[IN_DIM];
    const int tid = threadIdx.x;
    const int c   = blockIdx.x;                  // 0..63
    for (int idx = tid; idx < IN_DIM / 4; idx += 256)
        ((float4*)d_lds)[idx] = ((const float4*)(down + c * IN_DIM))[idx];
    __syncthreads();
    const float ls  = lora_scales[c >> 4];
    const int wave = tid >> 6, lane = tid & 63;
    for (int t = wave; t < T_DIM; t += 4) {
        const float4* xr = (const float4*)(x + t * IN_DIM);
        float sum = 0.f;
        for (int j = lane; j < IN_DIM / 4; j += 64) {
            float4 xv = xr[j];
            float4 dv = ((const float4*)d_lds)[j];
            sum += xv.x * dv.x + xv.y * dv.y + xv.z * dv.z + xv.w * dv.w;
        }
        for (int off = 32; off; off >>= 1) sum += __shfl_down(sum, off);
        if (lane == 0) tbuf[t * LR + c] = sum * ls;
    }
}

// ---------------------------------------------------------------------------
// Kernel 2: y = x @ dequant(qW)^T + t @ up'^T
//   64x48 tile per block, K streamed in 128-wide chunks (1 AWQ group each).
//   Register-prefetch -> single LDS buffer; bf16 MFMA 16x16x32.
//   LoRA applied as one extra rank-64 K-chunk through the same MFMA path.
// ---------------------------------------------------------------------------
__global__ __launch_bounds__(256) void awq_lora_gemm_kernel(
    const float* __restrict__ x, const int* __restrict__ qweight,
    const int* __restrict__ zeros, const float* __restrict__ scales,
    const float* __restrict__ up, const float* __restrict__ tbuf,
    float* __restrict__ out)
{
    __shared__ __bf16 x_lds[T_DIM][LDS_STRIDE];   // 17408 B
    __shared__ __bf16 w_lds[BN][LDS_STRIDE];      // 13056 B
    __shared__ float  s_lds[BN][NGROUP];          //  6144 B
    __shared__ float  zs_lds[BN][NGROUP];         //  6144 B

    const int tid  = threadIdx.x;
    const int n0   = blockIdx.x * BN;
    const int wave = tid >> 6, lane = tid & 63;
    const int lrow = lane & 15, quad = lane >> 4;

    // per-thread staging geometry: 48x128 q ints (6 x int4), 64x128 x floats (8 x float4)
    int qrow[6], qcol[6], qoff[6];
#pragma unroll
    for (int it = 0; it < 6; ++it) {
        int e = (it * 256 + tid) * 4;
        qrow[it] = e >> 7; qcol[it] = e & 127;
        qoff[it] = (n0 + qrow[it]) * IN_DIM + qcol[it];
    }
    int xrow[8], xcol[8], xoff[8];
#pragma unroll
    for (int it = 0; it < 8; ++it) {
        int e = (it * 256 + tid) * 4;
        xrow[it] = e >> 7; xcol[it] = e & 127;
        xoff[it] = xrow[it] * IN_DIM + xcol[it];
    }

    // stage scales / (-zero*scale) for this block's 48 rows, all 32 groups
    for (int idx = tid; idx < BN * NGROUP; idx += 256) {
        int row = idx >> 5, g = idx & 31;
        float s = scales[(n0 + row) * NGROUP + g];
        float z = (float)zeros[(n0 + row) * NGROUP + g];
        s_lds[row][g]  = s;
        zs_lds[row][g] = -z * s;
    }

    // prefetch chunk 0 into registers
    int4   qr[6];
    float4 xr[8];
#pragma unroll
    for (int it = 0; it < 6; ++it) qr[it] = *(const int4*)(qweight + qoff[it]);
#pragma unroll
    for (int it = 0; it < 8; ++it) xr[it] = *(const float4*)(x + xoff[it]);

    f32x4 acc[3] = {{0.f,0.f,0.f,0.f},{0.f,0.f,0.f,0.f},{0.f,0.f,0.f,0.f}};

    __syncthreads();   // s_lds / zs_lds ready

    for (int ch = 0; ch < NCHUNK; ++ch) {
        // dequant q -> bf16 LDS; convert x -> bf16 LDS
#pragma unroll
        for (int it = 0; it < 6; ++it) {
            float s  = s_lds[qrow[it]][ch];
            float zs = zs_lds[qrow[it]][ch];
            bf16x4 w;
            w[0] = (__bf16)((float)qr[it].x * s + zs);
            w[1] = (__bf16)((float)qr[it].y * s + zs);
            w[2] = (__bf16)((float)qr[it].z * s + zs);
            w[3] = (__bf16)((float)qr[it].w * s + zs);
            *(bf16x4*)&w_lds[qrow[it]][qcol[it]] = w;
        }
#pragma unroll
        for (int it = 0; it < 8; ++it) {
            bf16x4 v;
            v[0] = (__bf16)xr[it].x; v[1] = (__bf16)xr[it].y;
            v[2] = (__bf16)xr[it].z; v[3] = (__bf16)xr[it].w;
            *(bf16x4*)&x_lds[xrow[it]][xcol[it]] = v;
        }
        __syncthreads();

        // issue next chunk's global loads now; they drain while we MFMA
        if (ch + 1 < NCHUNK) {
            const int k0 = (ch + 1) * BK;
#pragma unroll
            for (int it = 0; it < 6; ++it) qr[it] = *(const int4*)(qweight + qoff[it] + k0);
#pragma unroll
            for (int it = 0; it < 8; ++it) xr[it] = *(const float4*)(x + xoff[it] + k0);
        }

#pragma unroll
        for (int kk = 0; kk < 4; ++kk) {
            const int ko = kk * 32 + quad * 8;
            bf16x8 a  = *(const bf16x8*)&x_lds[wave * 16 + lrow][ko];
            bf16x8 b0 = *(const bf16x8*)&w_lds[lrow][ko];
            bf16x8 b1 = *(const bf16x8*)&w_lds[16 + lrow][ko];
            bf16x8 b2 = *(const bf16x8*)&w_lds[32 + lrow][ko];
            acc[0] = __builtin_amdgcn_mfma_f32_16x16x32_bf16(a, b0, acc[0], 0, 0, 0);
            acc[1] = __builtin_amdgcn_mfma_f32_16x16x32_bf16(a, b1, acc[1], 0, 0, 0);
            acc[2] = __builtin_amdgcn_mfma_f32_16x16x32_bf16(a, b2, acc[2], 0, 0, 0);
        }
        __syncthreads();
    }

    // ---- LoRA as one extra rank-64 K chunk: A = t (lora_scale folded), B = up' ----
    for (int idx = tid; idx < T_DIM * LR; idx += 256)
        x_lds[idx >> 6][idx & 63] = (__bf16)tbuf[idx];
    for (int idx = tid; idx < BN * LR; idx += 256) {
        int oo = idx >> 6, cc = idx & 63;
        int l = cc >> 4, r = cc & 15;
        w_lds[oo][cc] = (__bf16)up[(l * OUT_DIM + n0 + oo) * R_DIM + r];
    }
    __syncthreads();
#pragma unroll
    for (int kk = 0; kk < 2; ++kk) {
        const int ko = kk * 32 + quad * 8;
        bf16x8 a  = *(const bf16x8*)&x_lds[wave * 16 + lrow][ko];
        bf16x8 b0 = *(const bf16x8*)&w_lds[lrow][ko];
        bf16x8 b1 = *(const bf16x8*)&w_lds[16 + lrow][ko];
        bf16x8 b2 = *(const bf16x8*)&w_lds[32 + lrow][ko];
        acc[0] = __builtin_amdgcn_mfma_f32_16x16x32_bf16(a, b0, acc[0], 0, 0, 0);
        acc[1] = __builtin_amdgcn_mfma_f32_16x16x32_bf16(a, b1, acc[1], 0, 0, 0);
        acc[2] = __builtin_amdgcn_mfma_f32_16x16x32_bf16(a, b2, acc[2], 0, 0, 0);
    }

    // epilogue: C/D layout (m89): col = lane&15 (o), row = quad*4 + reg (t)
#pragma unroll
    for (int nt = 0; nt < 3; ++nt) {
        const int o = n0 + nt * 16 + lrow;
#pragma unroll
        for (int i = 0; i < 4; ++i) {
            const int t = wave * 16 + quad * 4 + i;
            out[t * OUT_DIM + o] = acc[nt][i];
        }
    }
}

// ---------------------------------------------------------------------------
extern "C" void kernel_launch(void* const* d_in, const int* in_sizes, int n_in,
                              void* d_out, int out_size, void* d_ws, size_t ws_size,
                              hipStream_t stream) {
    const float* x           = (const float*)d_in[0];
    const int*   qweight     = (const int*)d_in[1];
    const int*   zeros       = (const int*)d_in[2];
    const float* scales      = (const float*)d_in[3];
    const float* up          = (const float*)d_in[4];
    const float* down        = (const float*)d_in[5];
    const float* lora_scales = (const float*)d_in[6];
    float* out  = (float*)d_out;
    float* tbuf = (float*)d_ws;   // 64*64 fp32 = 16 KiB

    hipLaunchKernelGGL(lora_down_kernel, dim3(LR), dim3(256), 0, stream,
                       x, down, lora_scales, tbuf);
    hipLaunchKernelGGL(awq_lora_gemm_kernel, dim3(OUT_DIM / BN), dim3(256), 0, stream,
                       x, qweight, zeros, scales, up, tbuf, out);
}

// Round 2
// 311.622 us; speedup vs baseline: 1.2873x; 1.2873x over previous
//
#include <hip/hip_runtime.h>
#include <hip/hip_bf16.h>

#define T_DIM   64
#define IN_DIM  4096
#define OUT_DIM 12288
#define NGROUP  32      // IN/GS
#define R_DIM   16
#define LR      64      // L*R

#define BN 16           // out-cols per block -> grid = 12288/16 = 768 = 3 blocks/CU
#define BK 128          // k per chunk (== group size GS)
#define NCHUNK (IN_DIM / BK)   // 32
#define LDS_STRIDE (BK + 8)    // +8 bf16 pad: 16B-aligned rows, breaks pow2 bank stride

#define KSPLIT 8
#define KSLICE (IN_DIM / KSPLIT)   // 512

// ws layout: [0,128KB) lora partials fp32 [KSPLIT][64][64]; [128KB,...) x in bf16 [64][4096]
#define PART_FLOATS (KSPLIT * T_DIM * LR)      // 32768 floats = 128 KiB
#define XBF_BYTE_OFF (PART_FLOATS * 4)

typedef __bf16 bf16x4 __attribute__((ext_vector_type(4)));
typedef __bf16 bf16x8 __attribute__((ext_vector_type(8)));
typedef float  f32x4  __attribute__((ext_vector_type(4)));

// ---------------------------------------------------------------------------
// Kernel 1 (prep): blocks 0..63 convert x row -> bf16; blocks 64..575 compute
// K-split LoRA-down partials part[ks][t][c] = ls_c * dot(x[t,slice], down[c,slice])
// ---------------------------------------------------------------------------
__global__ __launch_bounds__(256) void prep_kernel(
    const float* __restrict__ x, const float* __restrict__ down,
    const float* __restrict__ lora_scales, float* __restrict__ part,
    __bf16* __restrict__ xbf)
{
    __shared__ float d_lds[KSLICE];
    const int tid = threadIdx.x;
    const int bid = blockIdx.x;

    if (bid < T_DIM) {
        // convert x row `bid` to bf16 (whole block returns together; no barrier taken)
        const float4* xr = (const float4*)(x + bid * IN_DIM);
        __bf16* dst = xbf + bid * IN_DIM;
#pragma unroll
        for (int it = 0; it < 4; ++it) {
            int j = it * 256 + tid;
            float4 v = xr[j];
            bf16x4 b;
            b[0] = (__bf16)v.x; b[1] = (__bf16)v.y;
            b[2] = (__bf16)v.z; b[3] = (__bf16)v.w;
            *(bf16x4*)(dst + j * 4) = b;
        }
        return;
    }

    const int p  = bid - T_DIM;        // 0..511
    const int c  = p & 63;             // lora column (l*16+r)
    const int ks = p >> 6;             // k-slice 0..7
    const float* dsl = down + c * IN_DIM + ks * KSLICE;
    for (int j = tid; j < KSLICE / 4; j += 256)
        ((float4*)d_lds)[j] = ((const float4*)dsl)[j];
    __syncthreads();
    const float ls = lora_scales[c >> 4];
    const int wave = tid >> 6, lane = tid & 63;
    for (int t = wave; t < T_DIM; t += 4) {
        const float4* xr = (const float4*)(x + t * IN_DIM + ks * KSLICE);
        float sum = 0.f;
#pragma unroll
        for (int j = 0; j < 2; ++j) {
            float4 xv = xr[lane + j * 64];
            float4 dv = ((const float4*)d_lds)[lane + j * 64];
            sum += xv.x * dv.x + xv.y * dv.y + xv.z * dv.z + xv.w * dv.w;
        }
        for (int off = 32; off; off >>= 1) sum += __shfl_down(sum, off);
        if (lane == 0) part[(ks * T_DIM + t) * LR + c] = sum * ls;
    }
}

// ---------------------------------------------------------------------------
// Kernel 2: y = x @ dequant(qW)^T + t @ up'^T
//   64x16 tile per block (grid 768 = 3 blocks/CU), K in 128-wide chunks,
//   register prefetch -> DOUBLE-buffered LDS (1 barrier/chunk), bf16 MFMA.
//   LoRA applied as one extra rank-64 K-chunk (t reduced from partials here).
// ---------------------------------------------------------------------------
__global__ __launch_bounds__(256) void awq_lora_gemm_kernel(
    const __bf16* __restrict__ xbf, const int* __restrict__ qweight,
    const int* __restrict__ zeros, const float* __restrict__ scales,
    const float* __restrict__ up, const float* __restrict__ part,
    float* __restrict__ out)
{
    __shared__ __bf16 x_lds[2][T_DIM][LDS_STRIDE];   // 34816 B
    __shared__ __bf16 w_lds[2][BN][LDS_STRIDE];      //  8704 B
    __shared__ float  s_lds[BN][NGROUP];             //  2048 B
    __shared__ float  zs_lds[BN][NGROUP];            //  2048 B

    const int tid  = threadIdx.x;
    const int n0   = blockIdx.x * BN;
    const int wave = tid >> 6, lane = tid & 63;
    const int lrow = lane & 15, quad = lane >> 4;

    // staging geometry: q = 16x128 ints (2 x int4/thread), x = 64x128 bf16 (4 x bf16x8/thread)
    int qrow[2], qcol[2], qoff[2];
#pragma unroll
    for (int it = 0; it < 2; ++it) {
        int e = (it * 256 + tid) * 4;
        qrow[it] = e >> 7; qcol[it] = e & 127;
        qoff[it] = (n0 + qrow[it]) * IN_DIM + qcol[it];
    }
    int xrow[4], xcu[4], xoff[4];
#pragma unroll
    for (int it = 0; it < 4; ++it) {
        int e16 = it * 256 + tid;          // 16B units of the 64x128 tile
        xrow[it] = e16 >> 4; xcu[it] = e16 & 15;
        xoff[it] = xrow[it] * IN_DIM + xcu[it] * 8;
    }

    // stage scales / (-zero*scale): 16 rows x 32 groups
#pragma unroll
    for (int it = 0; it < 2; ++it) {
        int idx = it * 256 + tid;
        int row = idx >> 5, g = idx & 31;
        float s = scales[(n0 + row) * NGROUP + g];
        float z = (float)zeros[(n0 + row) * NGROUP + g];
        s_lds[row][g]  = s;
        zs_lds[row][g] = -z * s;
    }

    // prefetch chunk 0
    int4   qr[2];
    bf16x8 xr[4];
#pragma unroll
    for (int it = 0; it < 2; ++it) qr[it] = *(const int4*)(qweight + qoff[it]);
#pragma unroll
    for (int it = 0; it < 4; ++it) xr[it] = *(const bf16x8*)(xbf + xoff[it]);

    f32x4 acc = {0.f, 0.f, 0.f, 0.f};

    __syncthreads();   // s_lds / zs_lds ready

    for (int ch = 0; ch < NCHUNK; ++ch) {
        const int b = ch & 1;
        // dequant q -> bf16 LDS; copy x bf16 -> LDS
#pragma unroll
        for (int it = 0; it < 2; ++it) {
            float s  = s_lds[qrow[it]][ch];
            float zs = zs_lds[qrow[it]][ch];
            bf16x4 w;
            w[0] = (__bf16)((float)qr[it].x * s + zs);
            w[1] = (__bf16)((float)qr[it].y * s + zs);
            w[2] = (__bf16)((float)qr[it].z * s + zs);
            w[3] = (__bf16)((float)qr[it].w * s + zs);
            *(bf16x4*)&w_lds[b][qrow[it]][qcol[it]] = w;
        }
#pragma unroll
        for (int it = 0; it < 4; ++it)
            *(bf16x8*)&x_lds[b][xrow[it]][xcu[it] * 8] = xr[it];
        __syncthreads();   // the ONLY barrier per chunk (double buffer)

        // issue next chunk's global loads; they drain during MFMA
        if (ch + 1 < NCHUNK) {
            const int k0 = (ch + 1) * BK;
#pragma unroll
            for (int it = 0; it < 2; ++it) qr[it] = *(const int4*)(qweight + qoff[it] + k0);
#pragma unroll
            for (int it = 0; it < 4; ++it) xr[it] = *(const bf16x8*)(xbf + xoff[it] + k0);
        }

#pragma unroll
        for (int kk = 0; kk < 4; ++kk) {
            const int ko = kk * 32 + quad * 8;
            bf16x8 a  = *(const bf16x8*)&x_lds[b][wave * 16 + lrow][ko];
            bf16x8 b0 = *(const bf16x8*)&w_lds[b][lrow][ko];
            acc = __builtin_amdgcn_mfma_f32_16x16x32_bf16(a, b0, acc, 0, 0, 0);
        }
    }

    // ---- LoRA as one extra rank-64 K chunk (buffer 0 is free: last chunk used buf 1) ----
    // reduce the 8 K-split partials -> t (bf16) into x_lds[0]
    {
        const f32x4* p4 = (const f32x4*)part;
#pragma unroll
        for (int it = 0; it < 4; ++it) {
            int u = it * 256 + tid;            // float4 index into [64][64]
            f32x4 s = p4[u];
#pragma unroll
            for (int p = 1; p < KSPLIT; ++p) s += p4[p * 1024 + u];
            bf16x4 bv;
            bv[0] = (__bf16)s[0]; bv[1] = (__bf16)s[1];
            bv[2] = (__bf16)s[2]; bv[3] = (__bf16)s[3];
            *(bf16x4*)&x_lds[0][u >> 4][(u & 15) * 4] = bv;
        }
    }
#pragma unroll
    for (int it = 0; it < 4; ++it) {
        int idx = it * 256 + tid;              // 16 x 64 up' tile
        int oo = idx >> 6, cc = idx & 63;
        int l = cc >> 4, r = cc & 15;
        w_lds[0][oo][cc] = (__bf16)up[(l * OUT_DIM + n0 + oo) * R_DIM + r];
    }
    __syncthreads();
#pragma unroll
    for (int kk = 0; kk < 2; ++kk) {
        const int ko = kk * 32 + quad * 8;
        bf16x8 a  = *(const bf16x8*)&x_lds[0][wave * 16 + lrow][ko];
        bf16x8 b0 = *(const bf16x8*)&w_lds[0][lrow][ko];
        acc = __builtin_amdgcn_mfma_f32_16x16x32_bf16(a, b0, acc, 0, 0, 0);
    }

    // epilogue: C/D layout (m89): col = lane&15 (o), row = quad*4 + reg (t)
    const int o = n0 + lrow;
#pragma unroll
    for (int i = 0; i < 4; ++i) {
        const int t = wave * 16 + quad * 4 + i;
        out[t * OUT_DIM + o] = acc[i];
    }
}

// ---------------------------------------------------------------------------
extern "C" void kernel_launch(void* const* d_in, const int* in_sizes, int n_in,
                              void* d_out, int out_size, void* d_ws, size_t ws_size,
                              hipStream_t stream) {
    const float* x           = (const float*)d_in[0];
    const int*   qweight     = (const int*)d_in[1];
    const int*   zeros       = (const int*)d_in[2];
    const float* scales      = (const float*)d_in[3];
    const float* up          = (const float*)d_in[4];
    const float* down        = (const float*)d_in[5];
    const float* lora_scales = (const float*)d_in[6];
    float*  out  = (float*)d_out;
    float*  part = (float*)d_ws;                              // 128 KiB
    __bf16* xbf  = (__bf16*)((char*)d_ws + XBF_BYTE_OFF);     // 512 KiB

    hipLaunchKernelGGL(prep_kernel, dim3(T_DIM + 64 * KSPLIT), dim3(256), 0, stream,
                       x, down, lora_scales, part, xbf);
    hipLaunchKernelGGL(awq_lora_gemm_kernel, dim3(OUT_DIM / BN), dim3(256), 0, stream,
                       xbf, qweight, zeros, scales, up, part, out);
}

// Round 3
// 306.499 us; speedup vs baseline: 1.3088x; 1.0167x over previous
//
#include <hip/hip_runtime.h>
#include <hip/hip_bf16.h>

#define T_DIM   64
#define IN_DIM  4096
#define OUT_DIM 12288
#define NGROUP  32      // IN/GS
#define R_DIM   16
#define LR      64      // L*R

#define BN 16           // out-cols per block -> grid = 12288/16 = 768 = 3 blocks/CU
#define BK 128          // k per chunk (== group size GS)
#define NCHUNK (IN_DIM / BK)   // 32
#define LDS_STRIDE (BK + 8)    // +8 bf16 pad: 16B-aligned rows, breaks pow2 bank stride

#define KSPLIT 8
#define KSLICE (IN_DIM / KSPLIT)   // 512

// ws layout: [0,128KB) lora partials fp32 [KSPLIT][64][64]; [128KB,...) x in bf16 [64][4096]
#define PART_FLOATS (KSPLIT * T_DIM * LR)      // 32768 floats = 128 KiB
#define XBF_BYTE_OFF (PART_FLOATS * 4)

typedef __bf16 bf16x4 __attribute__((ext_vector_type(4)));
typedef __bf16 bf16x8 __attribute__((ext_vector_type(8)));
typedef float  f32x4  __attribute__((ext_vector_type(4)));

// ---------------------------------------------------------------------------
// Kernel 1 (prep): blocks 0..63 convert x row -> bf16; blocks 64..575 compute
// K-split LoRA-down partials part[ks][t][c] = ls_c * dot(x[t,slice], down[c,slice])
// ---------------------------------------------------------------------------
__global__ __launch_bounds__(256) void prep_kernel(
    const float* __restrict__ x, const float* __restrict__ down,
    const float* __restrict__ lora_scales, float* __restrict__ part,
    __bf16* __restrict__ xbf)
{
    __shared__ float d_lds[KSLICE];
    const int tid = threadIdx.x;
    const int bid = blockIdx.x;

    if (bid < T_DIM) {
        // convert x row `bid` to bf16
        const float4* xr = (const float4*)(x + bid * IN_DIM);
        __bf16* dst = xbf + bid * IN_DIM;
#pragma unroll
        for (int it = 0; it < 4; ++it) {
            int j = it * 256 + tid;
            float4 v = xr[j];
            bf16x4 b;
            b[0] = (__bf16)v.x; b[1] = (__bf16)v.y;
            b[2] = (__bf16)v.z; b[3] = (__bf16)v.w;
            *(bf16x4*)(dst + j * 4) = b;
        }
        return;
    }

    const int p  = bid - T_DIM;        // 0..511
    const int c  = p & 63;             // lora column (l*16+r)
    const int ks = p >> 6;             // k-slice 0..7
    const float* dsl = down + c * IN_DIM + ks * KSLICE;
    for (int j = tid; j < KSLICE / 4; j += 256)
        ((float4*)d_lds)[j] = ((const float4*)dsl)[j];
    __syncthreads();
    const float ls = lora_scales[c >> 4];
    const int wave = tid >> 6, lane = tid & 63;
    // two t-rows per iteration: independent shuffle-reduce chains (ILP)
    for (int t = wave * 2; t < T_DIM; t += 8) {
        const float4* xr0 = (const float4*)(x + t * IN_DIM + ks * KSLICE);
        const float4* xr1 = (const float4*)(x + (t + 1) * IN_DIM + ks * KSLICE);
        float sa = 0.f, sb = 0.f;
#pragma unroll
        for (int j = 0; j < 2; ++j) {
            float4 dv  = ((const float4*)d_lds)[lane + j * 64];
            float4 xa  = xr0[lane + j * 64];
            float4 xb  = xr1[lane + j * 64];
            sa += xa.x * dv.x + xa.y * dv.y + xa.z * dv.z + xa.w * dv.w;
            sb += xb.x * dv.x + xb.y * dv.y + xb.z * dv.z + xb.w * dv.w;
        }
        for (int off = 32; off; off >>= 1) {
            sa += __shfl_down(sa, off);
            sb += __shfl_down(sb, off);
        }
        if (lane == 0) {
            part[(ks * T_DIM + t) * LR + c]     = sa * ls;
            part[(ks * T_DIM + t + 1) * LR + c] = sb * ls;
        }
    }
}

// ---------------------------------------------------------------------------
// Kernel 2: y = x @ dequant(qW)^T + t @ up'^T
//   64x16 tile per block (grid 768 = 3 blocks/CU), K in 128-wide chunks.
//   TWO register load-sets + double-buffered LDS, unroll-by-2 chunk loop:
//   the vmcnt wait for one set leaves the other set's chunk in flight, so
//   each block always has >=1 full 24KB chunk outstanding (HBM stays queued).
//   LoRA applied as one extra rank-64 K-chunk.
// ---------------------------------------------------------------------------
__global__ __launch_bounds__(256) void awq_lora_gemm_kernel(
    const __bf16* __restrict__ xbf, const int* __restrict__ qweight,
    const int* __restrict__ zeros, const float* __restrict__ scales,
    const float* __restrict__ up, const float* __restrict__ part,
    float* __restrict__ out)
{
    __shared__ __bf16 x_lds[2][T_DIM][LDS_STRIDE];   // 34816 B
    __shared__ __bf16 w_lds[2][BN][LDS_STRIDE];      //  8704 B
    __shared__ float  s_lds[BN][NGROUP];             //  2048 B
    __shared__ float  zs_lds[BN][NGROUP];            //  2048 B

    const int tid  = threadIdx.x;
    const int n0   = blockIdx.x * BN;
    const int wave = tid >> 6, lane = tid & 63;
    const int lrow = lane & 15, quad = lane >> 4;

    // staging geometry: q = 16x128 ints (2 x int4/thread), x = 64x128 bf16 (4 x bf16x8/thread)
    int qrow[2], qcol[2], qoff[2];
#pragma unroll
    for (int it = 0; it < 2; ++it) {
        int e = (it * 256 + tid) * 4;
        qrow[it] = e >> 7; qcol[it] = e & 127;
        qoff[it] = (n0 + qrow[it]) * IN_DIM + qcol[it];
    }
    int xrow[4], xcu[4], xoff[4];
#pragma unroll
    for (int it = 0; it < 4; ++it) {
        int e16 = it * 256 + tid;          // 16B units of the 64x128 tile
        xrow[it] = e16 >> 4; xcu[it] = e16 & 15;
        xoff[it] = xrow[it] * IN_DIM + xcu[it] * 8;
    }

    // stage scales / (-zero*scale): 16 rows x 32 groups
#pragma unroll
    for (int it = 0; it < 2; ++it) {
        int idx = it * 256 + tid;
        int row = idx >> 5, g = idx & 31;
        float s = scales[(n0 + row) * NGROUP + g];
        float z = (float)zeros[(n0 + row) * NGROUP + g];
        s_lds[row][g]  = s;
        zs_lds[row][g] = -z * s;
    }

    // two register load-sets; prologue loads chunks 0 and 1
    int4   qr0[2], qr1[2];
    bf16x8 xr0[4], xr1[4];
#pragma unroll
    for (int it = 0; it < 2; ++it) qr0[it] = *(const int4*)(qweight + qoff[it]);
#pragma unroll
    for (int it = 0; it < 4; ++it) xr0[it] = *(const bf16x8*)(xbf + xoff[it]);
#pragma unroll
    for (int it = 0; it < 2; ++it) qr1[it] = *(const int4*)(qweight + qoff[it] + BK);
#pragma unroll
    for (int it = 0; it < 4; ++it) xr1[it] = *(const bf16x8*)(xbf + xoff[it] + BK);

    f32x4 acc = {0.f, 0.f, 0.f, 0.f};

    __syncthreads();   // s_lds / zs_lds ready

    for (int ch = 0; ch < NCHUNK; ch += 2) {
        // ---- even chunk: set0 -> buf0 ----
#pragma unroll
        for (int it = 0; it < 2; ++it) {
            float s  = s_lds[qrow[it]][ch];
            float zs = zs_lds[qrow[it]][ch];
            bf16x4 w;
            w[0] = (__bf16)((float)qr0[it].x * s + zs);
            w[1] = (__bf16)((float)qr0[it].y * s + zs);
            w[2] = (__bf16)((float)qr0[it].z * s + zs);
            w[3] = (__bf16)((float)qr0[it].w * s + zs);
            *(bf16x4*)&w_lds[0][qrow[it]][qcol[it]] = w;
        }
#pragma unroll
        for (int it = 0; it < 4; ++it)
            *(bf16x8*)&x_lds[0][xrow[it]][xcu[it] * 8] = xr0[it];
        __syncthreads();
        if (ch + 2 < NCHUNK) {
            const int k0 = (ch + 2) * BK;
#pragma unroll
            for (int it = 0; it < 2; ++it) qr0[it] = *(const int4*)(qweight + qoff[it] + k0);
#pragma unroll
            for (int it = 0; it < 4; ++it) xr0[it] = *(const bf16x8*)(xbf + xoff[it] + k0);
        }
#pragma unroll
        for (int kk = 0; kk < 4; ++kk) {
            const int ko = kk * 32 + quad * 8;
            bf16x8 a  = *(const bf16x8*)&x_lds[0][wave * 16 + lrow][ko];
            bf16x8 b0 = *(const bf16x8*)&w_lds[0][lrow][ko];
            acc = __builtin_amdgcn_mfma_f32_16x16x32_bf16(a, b0, acc, 0, 0, 0);
        }

        // ---- odd chunk: set1 -> buf1 ----
#pragma unroll
        for (int it = 0; it < 2; ++it) {
            float s  = s_lds[qrow[it]][ch + 1];
            float zs = zs_lds[qrow[it]][ch + 1];
            bf16x4 w;
            w[0] = (__bf16)((float)qr1[it].x * s + zs);
            w[1] = (__bf16)((float)qr1[it].y * s + zs);
            w[2] = (__bf16)((float)qr1[it].z * s + zs);
            w[3] = (__bf16)((float)qr1[it].w * s + zs);
            *(bf16x4*)&w_lds[1][qrow[it]][qcol[it]] = w;
        }
#pragma unroll
        for (int it = 0; it < 4; ++it)
            *(bf16x8*)&x_lds[1][xrow[it]][xcu[it] * 8] = xr1[it];
        __syncthreads();
        if (ch + 3 < NCHUNK) {
            const int k0 = (ch + 3) * BK;
#pragma unroll
            for (int it = 0; it < 2; ++it) qr1[it] = *(const int4*)(qweight + qoff[it] + k0);
#pragma unroll
            for (int it = 0; it < 4; ++it) xr1[it] = *(const bf16x8*)(xbf + xoff[it] + k0);
        }
#pragma unroll
        for (int kk = 0; kk < 4; ++kk) {
            const int ko = kk * 32 + quad * 8;
            bf16x8 a  = *(const bf16x8*)&x_lds[1][wave * 16 + lrow][ko];
            bf16x8 b0 = *(const bf16x8*)&w_lds[1][lrow][ko];
            acc = __builtin_amdgcn_mfma_f32_16x16x32_bf16(a, b0, acc, 0, 0, 0);
        }
    }

    // ---- LoRA as one extra rank-64 K chunk (buf0 free after last odd chunk) ----
    {
        const f32x4* p4 = (const f32x4*)part;
#pragma unroll
        for (int it = 0; it < 4; ++it) {
            int u = it * 256 + tid;            // float4 index into [64][64]
            f32x4 s = p4[u];
#pragma unroll
            for (int p = 1; p < KSPLIT; ++p) s += p4[p * 1024 + u];
            bf16x4 bv;
            bv[0] = (__bf16)s[0]; bv[1] = (__bf16)s[1];
            bv[2] = (__bf16)s[2]; bv[3] = (__bf16)s[3];
            *(bf16x4*)&x_lds[0][u >> 4][(u & 15) * 4] = bv;
        }
    }
#pragma unroll
    for (int it = 0; it < 4; ++it) {
        int idx = it * 256 + tid;              // 16 x 64 up' tile
        int oo = idx >> 6, cc = idx & 63;
        int l = cc >> 4, r = cc & 15;
        w_lds[0][oo][cc] = (__bf16)up[(l * OUT_DIM + n0 + oo) * R_DIM + r];
    }
    __syncthreads();
#pragma unroll
    for (int kk = 0; kk < 2; ++kk) {
        const int ko = kk * 32 + quad * 8;
        bf16x8 a  = *(const bf16x8*)&x_lds[0][wave * 16 + lrow][ko];
        bf16x8 b0 = *(const bf16x8*)&w_lds[0][lrow][ko];
        acc = __builtin_amdgcn_mfma_f32_16x16x32_bf16(a, b0, acc, 0, 0, 0);
    }

    // epilogue: C/D layout (m89): col = lane&15 (o), row = quad*4 + reg (t)
    const int o = n0 + lrow;
#pragma unroll
    for (int i = 0; i < 4; ++i) {
        const int t = wave * 16 + quad * 4 + i;
        out[t * OUT_DIM + o] = acc[i];
    }
}

// ---------------------------------------------------------------------------
extern "C" void kernel_launch(void* const* d_in, const int* in_sizes, int n_in,
                              void* d_out, int out_size, void* d_ws, size_t ws_size,
                              hipStream_t stream) {
    const float* x           = (const float*)d_in[0];
    const int*   qweight     = (const int*)d_in[1];
    const int*   zeros       = (const int*)d_in[2];
    const float* scales      = (const float*)d_in[3];
    const float* up          = (const float*)d_in[4];
    const float* down        = (const float*)d_in[5];
    const float* lora_scales = (const float*)d_in[6];
    float*  out  = (float*)d_out;
    float*  part = (float*)d_ws;                              // 128 KiB
    __bf16* xbf  = (__bf16*)((char*)d_ws + XBF_BYTE_OFF);     // 512 KiB

    hipLaunchKernelGGL(prep_kernel, dim3(T_DIM + 64 * KSPLIT), dim3(256), 0, stream,
                       x, down, lora_scales, part, xbf);
    hipLaunchKernelGGL(awq_lora_gemm_kernel, dim3(OUT_DIM / BN), dim3(256), 0, stream,
                       xbf, qweight, zeros, scales, up, part, out);
}

// Round 4
// 302.823 us; speedup vs baseline: 1.3247x; 1.0121x over previous
//
#include <hip/hip_runtime.h>
#include <hip/hip_bf16.h>

#define T_DIM   64
#define IN_DIM  4096
#define OUT_DIM 12288
#define NGROUP  32      // IN/GS
#define R_DIM   16
#define LR      64      // L*R

#define BN 16           // out-cols per block -> grid = 12288/16 = 768 (3 blocks/CU)
#define BK 128          // k per chunk (== group size GS)
#define NCHUNK (IN_DIM / BK)   // 32
#define W_STRIDE (BK + 8)      // 136: +8 bf16 pad -> 4-bank shift/row, 2-way max (free)
#define T_STRIDE (LR + 8)      // 72

#define KSPLIT 8
#define KSLICE (IN_DIM / KSPLIT)   // 512

// ws layout: [0,128KB) lora partials fp32 [KSPLIT][64][64];
//            [128KB, 128KB+512KB) x in bf16, MFMA A-FRAGMENT-MAJOR:
//            frag(rt,kb,lane) at ((rt*128+kb)*64+lane)*8 holds
//            x[rt*16 + (lane&15)][kb*32 + (lane>>4)*8 + 0..7]
#define PART_FLOATS (KSPLIT * T_DIM * LR)      // 32768 floats = 128 KiB
#define XBF_BYTE_OFF (PART_FLOATS * 4)

typedef __bf16 bf16x4 __attribute__((ext_vector_type(4)));
typedef __bf16 bf16x8 __attribute__((ext_vector_type(8)));
typedef float  f32x4  __attribute__((ext_vector_type(4)));

// ---------------------------------------------------------------------------
// Kernel 1 (prep): blocks 0..63 convert x -> bf16 in A-fragment-major layout;
// blocks 64..575 compute K-split LoRA-down partials
// part[ks][t][c] = ls_c * dot(x[t,slice], down[c,slice])
// ---------------------------------------------------------------------------
__global__ __launch_bounds__(256) void prep_kernel(
    const float* __restrict__ x, const float* __restrict__ down,
    const float* __restrict__ lora_scales, float* __restrict__ part,
    __bf16* __restrict__ xbf2)
{
    const int tid = threadIdx.x;
    const int bid = blockIdx.x;

    if (bid < 64) {
        // fragment-major conversion: rt = row-tile (wave id in GEMM), kb = 32-wide k block
        const int rt = bid & 3;
        const int kb_base = (bid >> 2) * 8;      // 16 groups x 8 kb = 128 kb
        const int lane = tid & 63, w = tid >> 6;
        const int row  = rt * 16 + (lane & 15);
        const int qd   = lane >> 4;
#pragma unroll
        for (int i = 0; i < 2; ++i) {
            int kb   = kb_base + i * 4 + w;
            int col0 = kb * 32 + qd * 8;
            float4 v0 = *(const float4*)(x + row * IN_DIM + col0);
            float4 v1 = *(const float4*)(x + row * IN_DIM + col0 + 4);
            bf16x8 b;
            b[0] = (__bf16)v0.x; b[1] = (__bf16)v0.y;
            b[2] = (__bf16)v0.z; b[3] = (__bf16)v0.w;
            b[4] = (__bf16)v1.x; b[5] = (__bf16)v1.y;
            b[6] = (__bf16)v1.z; b[7] = (__bf16)v1.w;
            *(bf16x8*)(xbf2 + ((rt * 128 + kb) * 64 + lane) * 8) = b;
        }
        return;
    }

    __shared__ float d_lds[KSLICE];
    const int p  = bid - 64;           // 0..511
    const int c  = p & 63;             // lora column (l*16+r)
    const int ks = p >> 6;             // k-slice 0..7
    const float* dsl = down + c * IN_DIM + ks * KSLICE;
    for (int j = tid; j < KSLICE / 4; j += 256)
        ((float4*)d_lds)[j] = ((const float4*)dsl)[j];
    __syncthreads();
    const float ls = lora_scales[c >> 4];
    const int wave = tid >> 6, lane = tid & 63;
    for (int t = wave * 2; t < T_DIM; t += 8) {
        const float4* xr0 = (const float4*)(x + t * IN_DIM + ks * KSLICE);
        const float4* xr1 = (const float4*)(x + (t + 1) * IN_DIM + ks * KSLICE);
        float sa = 0.f, sb = 0.f;
#pragma unroll
        for (int j = 0; j < 2; ++j) {
            float4 dv = ((const float4*)d_lds)[lane + j * 64];
            float4 xa = xr0[lane + j * 64];
            float4 xb = xr1[lane + j * 64];
            sa += xa.x * dv.x + xa.y * dv.y + xa.z * dv.z + xa.w * dv.w;
            sb += xb.x * dv.x + xb.y * dv.y + xb.z * dv.z + xb.w * dv.w;
        }
        for (int off = 32; off; off >>= 1) {
            sa += __shfl_down(sa, off);
            sb += __shfl_down(sb, off);
        }
        if (lane == 0) {
            part[(ks * T_DIM + t) * LR + c]     = sa * ls;
            part[(ks * T_DIM + t + 1) * LR + c] = sb * ls;
        }
    }
}

// ---------------------------------------------------------------------------
// Kernel 2: y = x @ dequant(qW)^T + t @ up'^T
//   64x16 tile per block (grid 768), K in 128-wide chunks.
//   A-fragments loaded DIRECTLY from L2-resident fragment-major xbf2 into a
//   2-deep register pipeline (no x LDS round trip). Only the dequantized
//   w-tile double-buffers through LDS -> barrier critical path is tiny and
//   LDS/block is ~15.7 KB. Two load sets alternate so each vmcnt wait leaves
//   the other set's chunk in flight. LoRA applied as one extra rank-64 chunk.
// ---------------------------------------------------------------------------
__global__ __launch_bounds__(256, 4) void awq_lora_gemm_kernel(
    const __bf16* __restrict__ xbf2, const int* __restrict__ qweight,
    const int* __restrict__ zeros, const float* __restrict__ scales,
    const float* __restrict__ up, const float* __restrict__ part,
    float* __restrict__ out)
{
    __shared__ __bf16 w_lds[2][BN][W_STRIDE];   // 8704 B
    __shared__ __bf16 t_lds[T_DIM][T_STRIDE];   // 9216 B (tail only)
    __shared__ float  s_lds[BN][NGROUP];        // 2048 B
    __shared__ float  zs_lds[BN][NGROUP];       // 2048 B

    const int tid  = threadIdx.x;
    const int n0   = blockIdx.x * BN;
    const int wave = tid >> 6, lane = tid & 63;
    const int lrow = lane & 15, quad = lane >> 4;

    // q staging geometry: 16x128 ints = 2 x int4 / thread
    int qrow[2], qcol[2], qoff[2];
#pragma unroll
    for (int it = 0; it < 2; ++it) {
        int e = (it * 256 + tid) * 4;
        qrow[it] = e >> 7; qcol[it] = e & 127;
        qoff[it] = (n0 + qrow[it]) * IN_DIM + qcol[it];
    }

    // A geometry: frag(rt=wave, kb=ch*4+kk, lane) -> elem offset
    //   wave*65536 + ch*2048 + kk*512 + lane*8
    const __bf16* abase = xbf2 + wave * 65536 + lane * 8;

    // stage scales / (-zero*scale): 16 rows x 32 groups
#pragma unroll
    for (int it = 0; it < 2; ++it) {
        int idx = it * 256 + tid;
        int row = idx >> 5, g = idx & 31;
        float s = scales[(n0 + row) * NGROUP + g];
        float z = (float)zeros[(n0 + row) * NGROUP + g];
        s_lds[row][g]  = s;
        zs_lds[row][g] = -z * s;
    }

    // two load sets; prologue loads chunks 0 and 1
    int4   qr0[2], qr1[2];
    bf16x8 ar0[4], ar1[4];
#pragma unroll
    for (int it = 0; it < 2; ++it) qr0[it] = *(const int4*)(qweight + qoff[it]);
#pragma unroll
    for (int kk = 0; kk < 4; ++kk) ar0[kk] = *(const bf16x8*)(abase + kk * 512);
#pragma unroll
    for (int it = 0; it < 2; ++it) qr1[it] = *(const int4*)(qweight + qoff[it] + BK);
#pragma unroll
    for (int kk = 0; kk < 4; ++kk) ar1[kk] = *(const bf16x8*)(abase + 2048 + kk * 512);

    f32x4 acc = {0.f, 0.f, 0.f, 0.f};

    __syncthreads();   // s_lds / zs_lds ready

    for (int ch = 0; ch < NCHUNK; ch += 2) {
        // ---- even chunk: set0 -> w_lds[0] ----
#pragma unroll
        for (int it = 0; it < 2; ++it) {
            float s  = s_lds[qrow[it]][ch];
            float zs = zs_lds[qrow[it]][ch];
            bf16x4 w;
            w[0] = (__bf16)((float)qr0[it].x * s + zs);
            w[1] = (__bf16)((float)qr0[it].y * s + zs);
            w[2] = (__bf16)((float)qr0[it].z * s + zs);
            w[3] = (__bf16)((float)qr0[it].w * s + zs);
            *(bf16x4*)&w_lds[0][qrow[it]][qcol[it]] = w;
        }
        __syncthreads();
#pragma unroll
        for (int kk = 0; kk < 4; ++kk) {
            const int ko = kk * 32 + quad * 8;
            bf16x8 b0 = *(const bf16x8*)&w_lds[0][lrow][ko];
            acc = __builtin_amdgcn_mfma_f32_16x16x32_bf16(ar0[kk], b0, acc, 0, 0, 0);
        }
        if (ch + 2 < NCHUNK) {   // refill set0 (registers now free)
            const int k0 = (ch + 2) * BK;
#pragma unroll
            for (int it = 0; it < 2; ++it) qr0[it] = *(const int4*)(qweight + qoff[it] + k0);
#pragma unroll
            for (int kk = 0; kk < 4; ++kk) ar0[kk] = *(const bf16x8*)(abase + (ch + 2) * 2048 + kk * 512);
        }

        // ---- odd chunk: set1 -> w_lds[1] ----
#pragma unroll
        for (int it = 0; it < 2; ++it) {
            float s  = s_lds[qrow[it]][ch + 1];
            float zs = zs_lds[qrow[it]][ch + 1];
            bf16x4 w;
            w[0] = (__bf16)((float)qr1[it].x * s + zs);
            w[1] = (__bf16)((float)qr1[it].y * s + zs);
            w[2] = (__bf16)((float)qr1[it].z * s + zs);
            w[3] = (__bf16)((float)qr1[it].w * s + zs);
            *(bf16x4*)&w_lds[1][qrow[it]][qcol[it]] = w;
        }
        __syncthreads();
#pragma unroll
        for (int kk = 0; kk < 4; ++kk) {
            const int ko = kk * 32 + quad * 8;
            bf16x8 b0 = *(const bf16x8*)&w_lds[1][lrow][ko];
            acc = __builtin_amdgcn_mfma_f32_16x16x32_bf16(ar1[kk], b0, acc, 0, 0, 0);
        }
        if (ch + 3 < NCHUNK) {   // refill set1
            const int k0 = (ch + 3) * BK;
#pragma unroll
            for (int it = 0; it < 2; ++it) qr1[it] = *(const int4*)(qweight + qoff[it] + k0);
#pragma unroll
            for (int kk = 0; kk < 4; ++kk) ar1[kk] = *(const bf16x8*)(abase + (ch + 3) * 2048 + kk * 512);
        }
    }

    // ---- LoRA as one extra rank-64 K chunk ----
    // reduce the 8 K-split partials -> t (bf16) into t_lds
    {
        const f32x4* p4 = (const f32x4*)part;
#pragma unroll
        for (int it = 0; it < 4; ++it) {
            int u = it * 256 + tid;            // float4 index into [64][64]
            f32x4 s = p4[u];
#pragma unroll
            for (int p = 1; p < KSPLIT; ++p) s += p4[p * 1024 + u];
            bf16x4 bv;
            bv[0] = (__bf16)s[0]; bv[1] = (__bf16)s[1];
            bv[2] = (__bf16)s[2]; bv[3] = (__bf16)s[3];
            *(bf16x4*)&t_lds[u >> 4][(u & 15) * 4] = bv;
        }
    }
#pragma unroll
    for (int it = 0; it < 4; ++it) {
        int idx = it * 256 + tid;              // 16 x 64 up' tile
        int oo = idx >> 6, cc = idx & 63;
        int l = cc >> 4, r = cc & 15;
        w_lds[0][oo][cc] = (__bf16)up[(l * OUT_DIM + n0 + oo) * R_DIM + r];
    }
    __syncthreads();
#pragma unroll
    for (int kk = 0; kk < 2; ++kk) {
        const int ko = kk * 32 + quad * 8;
        bf16x8 a  = *(const bf16x8*)&t_lds[wave * 16 + lrow][ko];
        bf16x8 b0 = *(const bf16x8*)&w_lds[0][lrow][ko];
        acc = __builtin_amdgcn_mfma_f32_16x16x32_bf16(a, b0, acc, 0, 0, 0);
    }

    // epilogue: C/D layout (m89): col = lane&15 (o), row = quad*4 + reg (t)
    const int o = n0 + lrow;
#pragma unroll
    for (int i = 0; i < 4; ++i) {
        const int t = wave * 16 + quad * 4 + i;
        out[t * OUT_DIM + o] = acc[i];
    }
}

// ---------------------------------------------------------------------------
extern "C" void kernel_launch(void* const* d_in, const int* in_sizes, int n_in,
                              void* d_out, int out_size, void* d_ws, size_t ws_size,
                              hipStream_t stream) {
    const float* x           = (const float*)d_in[0];
    const int*   qweight     = (const int*)d_in[1];
    const int*   zeros       = (const int*)d_in[2];
    const float* scales      = (const float*)d_in[3];
    const float* up          = (const float*)d_in[4];
    const float* down        = (const float*)d_in[5];
    const float* lora_scales = (const float*)d_in[6];
    float*  out  = (float*)d_out;
    float*  part = (float*)d_ws;                              // 128 KiB
    __bf16* xbf2 = (__bf16*)((char*)d_ws + XBF_BYTE_OFF);     // 512 KiB, frag-major

    hipLaunchKernelGGL(prep_kernel, dim3(64 + 64 * KSPLIT), dim3(256), 0, stream,
                       x, down, lora_scales, part, xbf2);
    hipLaunchKernelGGL(awq_lora_gemm_kernel, dim3(OUT_DIM / BN), dim3(256), 0, stream,
                       xbf2, qweight, zeros, scales, up, part, out);
}

// Round 5
// 302.102 us; speedup vs baseline: 1.3278x; 1.0024x over previous
//
#include <hip/hip_runtime.h>
#include <hip/hip_bf16.h>

#define T_DIM   64
#define IN_DIM  4096
#define OUT_DIM 12288
#define NGROUP  32      // IN/GS
#define R_DIM   16
#define LR      64      // L*R

#define BN 16           // out-cols per block -> grid = 12288/16 = 768 (3 blocks/CU)
#define BK 128          // k per chunk (== group size GS)
#define NCHUNK (IN_DIM / BK)   // 32
#define W_STRIDE (BK + 8)      // 136: +8 bf16 pad -> 4-bank shift/row, 2-way max (free)
#define T_STRIDE (LR + 8)      // 72

#define KSPLIT 8
#define KSLICE (IN_DIM / KSPLIT)   // 512

// ws layout: [0,128KB) lora partials fp32 [KSPLIT][64][64];
//            [128KB, 128KB+512KB) x in bf16, MFMA A-FRAGMENT-MAJOR:
//            frag(rt,kb,lane) at ((rt*128+kb)*64+lane)*8 holds
//            x[rt*16 + (lane&15)][kb*32 + (lane>>4)*8 + 0..7]
#define PART_FLOATS (KSPLIT * T_DIM * LR)      // 32768 floats = 128 KiB
#define XBF_BYTE_OFF (PART_FLOATS * 4)

typedef __bf16 bf16x4 __attribute__((ext_vector_type(4)));
typedef __bf16 bf16x8 __attribute__((ext_vector_type(8)));
typedef float  f32x4  __attribute__((ext_vector_type(4)));

// Workgroup barrier that waits ONLY lgkmcnt(0) (LDS writes visible) and leaves
// global loads (vmcnt) IN FLIGHT. Legal here: all LDS staging data is produced
// by VALU from registers; global-load results get compiler-inserted per-use
// vmcnt waits. imm 0xC07F = vmcnt 63 (bits 3:0=0xF, 15:14=3), expcnt 7, lgkmcnt 0.
__device__ __forceinline__ void barrier_lgkm() {
    asm volatile("" ::: "memory");
    __builtin_amdgcn_s_waitcnt(0xC07F);
    __builtin_amdgcn_s_barrier();
    asm volatile("" ::: "memory");
}

// ---------------------------------------------------------------------------
// Kernel 1 (prep): blocks 0..63 convert x -> bf16 in A-fragment-major layout;
// blocks 64..575 compute K-split LoRA-down partials
// part[ks][t][c] = ls_c * dot(x[t,slice], down[c,slice])
// ---------------------------------------------------------------------------
__global__ __launch_bounds__(256) void prep_kernel(
    const float* __restrict__ x, const float* __restrict__ down,
    const float* __restrict__ lora_scales, float* __restrict__ part,
    __bf16* __restrict__ xbf2)
{
    const int tid = threadIdx.x;
    const int bid = blockIdx.x;

    if (bid < 64) {
        const int rt = bid & 3;
        const int kb_base = (bid >> 2) * 8;
        const int lane = tid & 63, w = tid >> 6;
        const int row  = rt * 16 + (lane & 15);
        const int qd   = lane >> 4;
#pragma unroll
        for (int i = 0; i < 2; ++i) {
            int kb   = kb_base + i * 4 + w;
            int col0 = kb * 32 + qd * 8;
            float4 v0 = *(const float4*)(x + row * IN_DIM + col0);
            float4 v1 = *(const float4*)(x + row * IN_DIM + col0 + 4);
            bf16x8 b;
            b[0] = (__bf16)v0.x; b[1] = (__bf16)v0.y;
            b[2] = (__bf16)v0.z; b[3] = (__bf16)v0.w;
            b[4] = (__bf16)v1.x; b[5] = (__bf16)v1.y;
            b[6] = (__bf16)v1.z; b[7] = (__bf16)v1.w;
            *(bf16x8*)(xbf2 + ((rt * 128 + kb) * 64 + lane) * 8) = b;
        }
        return;
    }

    __shared__ float d_lds[KSLICE];
    const int p  = bid - 64;
    const int c  = p & 63;
    const int ks = p >> 6;
    const float* dsl = down + c * IN_DIM + ks * KSLICE;
    for (int j = tid; j < KSLICE / 4; j += 256)
        ((float4*)d_lds)[j] = ((const float4*)dsl)[j];
    __syncthreads();
    const float ls = lora_scales[c >> 4];
    const int wave = tid >> 6, lane = tid & 63;
    for (int t = wave * 2; t < T_DIM; t += 8) {
        const float4* xr0 = (const float4*)(x + t * IN_DIM + ks * KSLICE);
        const float4* xr1 = (const float4*)(x + (t + 1) * IN_DIM + ks * KSLICE);
        float sa = 0.f, sb = 0.f;
#pragma unroll
        for (int j = 0; j < 2; ++j) {
            float4 dv = ((const float4*)d_lds)[lane + j * 64];
            float4 xa = xr0[lane + j * 64];
            float4 xb = xr1[lane + j * 64];
            sa += xa.x * dv.x + xa.y * dv.y + xa.z * dv.z + xa.w * dv.w;
            sb += xb.x * dv.x + xb.y * dv.y + xb.z * dv.z + xb.w * dv.w;
        }
        for (int off = 32; off; off >>= 1) {
            sa += __shfl_down(sa, off);
            sb += __shfl_down(sb, off);
        }
        if (lane == 0) {
            part[(ks * T_DIM + t) * LR + c]     = sa * ls;
            part[(ks * T_DIM + t + 1) * LR + c] = sb * ls;
        }
    }
}

// ---------------------------------------------------------------------------
// Kernel 2: y = x @ dequant(qW)^T + t @ up'^T
//   64x16 tile/block (grid 768, 3/CU). A-frags direct from L2-resident
//   frag-major xbf2; only dequantized w double-buffers through LDS.
//   Barriers are lgkm-only (see barrier_lgkm) so the 2-set q/A register
//   pipeline stays in flight across them; q refills issued right after
//   dequant consumes the registers (max DRAM lead time).
// ---------------------------------------------------------------------------
__global__ __launch_bounds__(256, 3) void awq_lora_gemm_kernel(
    const __bf16* __restrict__ xbf2, const int* __restrict__ qweight,
    const int* __restrict__ zeros, const float* __restrict__ scales,
    const float* __restrict__ up, const float* __restrict__ part,
    float* __restrict__ out)
{
    __shared__ __bf16 w_lds[2][BN][W_STRIDE];   // 8704 B
    __shared__ __bf16 t_lds[T_DIM][T_STRIDE];   // 9216 B (tail only)
    __shared__ float  s_lds[BN][NGROUP];        // 2048 B
    __shared__ float  zs_lds[BN][NGROUP];       // 2048 B

    const int tid  = threadIdx.x;
    const int n0   = blockIdx.x * BN;
    const int wave = tid >> 6, lane = tid & 63;
    const int lrow = lane & 15, quad = lane >> 4;

    // q staging geometry: 16x128 ints = 2 x int4 / thread
    int qrow[2], qcol[2], qoff[2];
#pragma unroll
    for (int it = 0; it < 2; ++it) {
        int e = (it * 256 + tid) * 4;
        qrow[it] = e >> 7; qcol[it] = e & 127;
        qoff[it] = (n0 + qrow[it]) * IN_DIM + qcol[it];
    }

    // A geometry: frag(rt=wave, kb=ch*4+kk, lane) -> elem offset
    const __bf16* abase = xbf2 + wave * 65536 + lane * 8;

    // stage scales / (-zero*scale): 16 rows x 32 groups
#pragma unroll
    for (int it = 0; it < 2; ++it) {
        int idx = it * 256 + tid;
        int row = idx >> 5, g = idx & 31;
        float s = scales[(n0 + row) * NGROUP + g];
        float z = (float)zeros[(n0 + row) * NGROUP + g];
        s_lds[row][g]  = s;
        zs_lds[row][g] = -z * s;
    }

    // two load sets; prologue loads chunks 0 and 1
    int4   qr0[2], qr1[2];
    bf16x8 ar0[4], ar1[4];
#pragma unroll
    for (int it = 0; it < 2; ++it) qr0[it] = *(const int4*)(qweight + qoff[it]);
#pragma unroll
    for (int kk = 0; kk < 4; ++kk) ar0[kk] = *(const bf16x8*)(abase + kk * 512);
#pragma unroll
    for (int it = 0; it < 2; ++it) qr1[it] = *(const int4*)(qweight + qoff[it] + BK);
#pragma unroll
    for (int kk = 0; kk < 4; ++kk) ar1[kk] = *(const bf16x8*)(abase + 2048 + kk * 512);

    f32x4 acc = {0.f, 0.f, 0.f, 0.f};

    barrier_lgkm();   // s_lds / zs_lds ready; prologue loads stay in flight

    for (int ch = 0; ch < NCHUNK; ch += 2) {
        // ---- even chunk: set0 -> w_lds[0] ----
#pragma unroll
        for (int it = 0; it < 2; ++it) {
            float s  = s_lds[qrow[it]][ch];
            float zs = zs_lds[qrow[it]][ch];
            bf16x4 w;
            w[0] = (__bf16)((float)qr0[it].x * s + zs);
            w[1] = (__bf16)((float)qr0[it].y * s + zs);
            w[2] = (__bf16)((float)qr0[it].z * s + zs);
            w[3] = (__bf16)((float)qr0[it].w * s + zs);
            *(bf16x4*)&w_lds[0][qrow[it]][qcol[it]] = w;
        }
        // qr0 consumed -> refill NOW (before barrier): max DRAM lead time
        if (ch + 2 < NCHUNK) {
            const int k0 = (ch + 2) * BK;
#pragma unroll
            for (int it = 0; it < 2; ++it) qr0[it] = *(const int4*)(qweight + qoff[it] + k0);
        }
        barrier_lgkm();
#pragma unroll
        for (int kk = 0; kk < 4; ++kk) {
            const int ko = kk * 32 + quad * 8;
            bf16x8 b0 = *(const bf16x8*)&w_lds[0][lrow][ko];
            acc = __builtin_amdgcn_mfma_f32_16x16x32_bf16(ar0[kk], b0, acc, 0, 0, 0);
        }
        if (ch + 2 < NCHUNK) {   // ar0 consumed -> refill (L2-resident, short latency)
#pragma unroll
            for (int kk = 0; kk < 4; ++kk) ar0[kk] = *(const bf16x8*)(abase + (ch + 2) * 2048 + kk * 512);
        }

        // ---- odd chunk: set1 -> w_lds[1] ----
#pragma unroll
        for (int it = 0; it < 2; ++it) {
            float s  = s_lds[qrow[it]][ch + 1];
            float zs = zs_lds[qrow[it]][ch + 1];
            bf16x4 w;
            w[0] = (__bf16)((float)qr1[it].x * s + zs);
            w[1] = (__bf16)((float)qr1[it].y * s + zs);
            w[2] = (__bf16)((float)qr1[it].z * s + zs);
            w[3] = (__bf16)((float)qr1[it].w * s + zs);
            *(bf16x4*)&w_lds[1][qrow[it]][qcol[it]] = w;
        }
        if (ch + 3 < NCHUNK) {
            const int k0 = (ch + 3) * BK;
#pragma unroll
            for (int it = 0; it < 2; ++it) qr1[it] = *(const int4*)(qweight + qoff[it] + k0);
        }
        barrier_lgkm();
#pragma unroll
        for (int kk = 0; kk < 4; ++kk) {
            const int ko = kk * 32 + quad * 8;
            bf16x8 b0 = *(const bf16x8*)&w_lds[1][lrow][ko];
            acc = __builtin_amdgcn_mfma_f32_16x16x32_bf16(ar1[kk], b0, acc, 0, 0, 0);
        }
        if (ch + 3 < NCHUNK) {
#pragma unroll
            for (int kk = 0; kk < 4; ++kk) ar1[kk] = *(const bf16x8*)(abase + (ch + 3) * 2048 + kk * 512);
        }
    }

    // ---- LoRA as one extra rank-64 K chunk ----
    {
        const f32x4* p4 = (const f32x4*)part;
#pragma unroll
        for (int it = 0; it < 4; ++it) {
            int u = it * 256 + tid;            // float4 index into [64][64]
            f32x4 s = p4[u];
#pragma unroll
            for (int p = 1; p < KSPLIT; ++p) s += p4[p * 1024 + u];
            bf16x4 bv;
            bv[0] = (__bf16)s[0]; bv[1] = (__bf16)s[1];
            bv[2] = (__bf16)s[2]; bv[3] = (__bf16)s[3];
            *(bf16x4*)&t_lds[u >> 4][(u & 15) * 4] = bv;
        }
    }
#pragma unroll
    for (int it = 0; it < 4; ++it) {
        int idx = it * 256 + tid;              // 16 x 64 up' tile
        int oo = idx >> 6, cc = idx & 63;
        int l = cc >> 4, r = cc & 15;
        w_lds[0][oo][cc] = (__bf16)up[(l * OUT_DIM + n0 + oo) * R_DIM + r];
    }
    barrier_lgkm();
#pragma unroll
    for (int kk = 0; kk < 2; ++kk) {
        const int ko = kk * 32 + quad * 8;
        bf16x8 a  = *(const bf16x8*)&t_lds[wave * 16 + lrow][ko];
        bf16x8 b0 = *(const bf16x8*)&w_lds[0][lrow][ko];
        acc = __builtin_amdgcn_mfma_f32_16x16x32_bf16(a, b0, acc, 0, 0, 0);
    }

    // epilogue: C/D layout (m89): col = lane&15 (o), row = quad*4 + reg (t)
    const int o = n0 + lrow;
#pragma unroll
    for (int i = 0; i < 4; ++i) {
        const int t = wave * 16 + quad * 4 + i;
        out[t * OUT_DIM + o] = acc[i];
    }
}

// ---------------------------------------------------------------------------
extern "C" void kernel_launch(void* const* d_in, const int* in_sizes, int n_in,
                              void* d_out, int out_size, void* d_ws, size_t ws_size,
                              hipStream_t stream) {
    const float* x           = (const float*)d_in[0];
    const int*   qweight     = (const int*)d_in[1];
    const int*   zeros       = (const int*)d_in[2];
    const float* scales      = (const float*)d_in[3];
    const float* up          = (const float*)d_in[4];
    const float* down        = (const float*)d_in[5];
    const float* lora_scales = (const float*)d_in[6];
    float*  out  = (float*)d_out;
    float*  part = (float*)d_ws;                              // 128 KiB
    __bf16* xbf2 = (__bf16*)((char*)d_ws + XBF_BYTE_OFF);     // 512 KiB, frag-major

    hipLaunchKernelGGL(prep_kernel, dim3(64 + 64 * KSPLIT), dim3(256), 0, stream,
                       x, down, lora_scales, part, xbf2);
    hipLaunchKernelGGL(awq_lora_gemm_kernel, dim3(OUT_DIM / BN), dim3(256), 0, stream,
                       xbf2, qweight, zeros, scales, up, part, out);
}